// Round 5
// baseline (735.906 us; speedup 1.0000x reference)
//
#include <hip/hip_runtime.h>

#define D 128
#define WTS 132  // padded LDS row stride for gemm staging

// ---------- helpers ----------

__device__ __forceinline__ unsigned int encf(float f) {
  unsigned int u = __float_as_uint(f);
  return (u & 0x80000000u) ? ~u : (u | 0x80000000u);
}
__device__ __forceinline__ float decf(unsigned int e) {
  return __uint_as_float((e & 0x80000000u) ? (e & 0x7FFFFFFFu) : ~e);
}

// JAX threefry2x32 (20 rounds), exact.
__device__ __forceinline__ void tf2x32(unsigned int k0, unsigned int k1,
                                       unsigned int& x0, unsigned int& x1) {
  unsigned int ks[3] = {k0, k1, k0 ^ k1 ^ 0x1BD11BDAu};
  x0 += ks[0]; x1 += ks[1];
  const unsigned int rotA[4] = {13u, 15u, 26u, 6u};
  const unsigned int rotB[4] = {17u, 29u, 16u, 24u};
#pragma unroll
  for (int g = 0; g < 5; ++g) {
    const unsigned int* rot = (g & 1) ? rotB : rotA;
#pragma unroll
    for (int i = 0; i < 4; ++i) {
      x0 += x1;
      x1 = (x1 << rot[i]) | (x1 >> (32u - rot[i]));
      x1 ^= x0;
    }
    x0 += ks[(g + 1) % 3];
    x1 += ks[(g + 2) % 3] + (unsigned int)(g + 1);
  }
}

// ---------- edge index normalization (int32 vs int64 runtime detect) ----------

__global__ __launch_bounds__(256) void norm_edges(const int* __restrict__ ei,
                                                  int* __restrict__ src32,
                                                  int* __restrict__ dst32,
                                                  int ne, int ns, int nm) {
  __shared__ int is64;
  if (threadIdx.x == 0) {
    int any = 0;
    for (int i = 1; i < 256; i += 2) any |= ei[i];
    is64 = (any == 0);
  }
  __syncthreads();
  int flag = is64;
  for (int i = blockIdx.x * 256 + threadIdx.x; i < ne; i += gridDim.x * 256) {
    int s = flag ? ei[2 * i] : ei[i];
    int d = flag ? ei[2 * ne + 2 * i] : ei[ne + i];
    s = s < 0 ? 0 : (s >= ns ? ns - 1 : s);
    d = d < 0 ? 0 : (d >= nm ? nm - 1 : d);
    src32[i] = s;
    dst32[i] = d;
  }
}

// ---------- GEMM v2: Y[r][c] = sum_k X[r][k] * W[c][k]  (fp32, D=128) ----------

__global__ __launch_bounds__(256) void gemm128(const float* __restrict__ X,
                                               const float* __restrict__ W,
                                               float* __restrict__ Y, int N) {
  __shared__ float WT[64 * WTS];  // WT[k'][c]
  int tid = threadIdx.x;
  int q = tid & 15;
  int rg = tid >> 4;

  for (long long r0 = (long long)blockIdx.x * 128; r0 < N;
       r0 += (long long)gridDim.x * 128) {
    float acc[8][8];
#pragma unroll
    for (int r = 0; r < 8; ++r)
#pragma unroll
      for (int c = 0; c < 8; ++c) acc[r][c] = 0.f;

    long long rbase = r0 + (long long)rg * 8;

#pragma unroll
    for (int phase = 0; phase < 2; ++phase) {
      const int kbase = phase * 64;
      __syncthreads();
      for (int i = tid; i < 2048; i += 256) {
        int c = i >> 4;
        int j = i & 15;
        float4 w4 = *(const float4*)(W + c * D + kbase + 4 * j);
        WT[(4 * j + 0) * WTS + c] = w4.x;
        WT[(4 * j + 1) * WTS + c] = w4.y;
        WT[(4 * j + 2) * WTS + c] = w4.z;
        WT[(4 * j + 3) * WTS + c] = w4.w;
      }
      __syncthreads();

      for (int k4 = 0; k4 < 64; k4 += 4) {
        float4 xr_[8];
#pragma unroll
        for (int r = 0; r < 8; ++r) {
          long long rr = rbase + r;
          if (rr >= N) rr = N - 1;
          xr_[r] = *(const float4*)(X + rr * D + kbase + k4);
        }
#pragma unroll
        for (int kk = 0; kk < 4; ++kk) {
          float4 wa = *(const float4*)(WT + (k4 + kk) * WTS + 4 * q);
          float4 wb = *(const float4*)(WT + (k4 + kk) * WTS + 64 + 4 * q);
#pragma unroll
          for (int r = 0; r < 8; ++r) {
            float xv = (&xr_[r].x)[kk];
            acc[r][0] += xv * wa.x; acc[r][1] += xv * wa.y;
            acc[r][2] += xv * wa.z; acc[r][3] += xv * wa.w;
            acc[r][4] += xv * wb.x; acc[r][5] += xv * wb.y;
            acc[r][6] += xv * wb.z; acc[r][7] += xv * wb.w;
          }
        }
      }
    }

#pragma unroll
    for (int r = 0; r < 8; ++r) {
      long long rr = rbase + r;
      if (rr < N) {
        float* yp = Y + rr * D;
        *(float4*)(yp + 4 * q) =
            make_float4(acc[r][0], acc[r][1], acc[r][2], acc[r][3]);
        *(float4*)(yp + 64 + 4 * q) =
            make_float4(acc[r][4], acc[r][5], acc[r][6], acc[r][7]);
      }
    }
  }
}

// ---------- edge pass 1: scores + segment max (quarter-wave/edge, unroll x2) ----

__global__ __launch_bounds__(256) void edge_scores(
    const float* __restrict__ xl, const float* __restrict__ xr,
    const int* __restrict__ src, const int* __restrict__ dst,
    const float* __restrict__ att, float* __restrict__ e_sc,
    unsigned int* __restrict__ m_enc, int ne) {
  int tid = threadIdx.x;
  int lane = tid & 63;
  int q = lane & 15;
  int sub = lane >> 4;
  int wid = (blockIdx.x * 256 + tid) >> 6;
  int nw = (gridDim.x * 256) >> 6;
  float4 a0 = ((const float4*)att)[2 * q];
  float4 a1 = ((const float4*)att)[2 * q + 1];
  for (int e0 = wid * 8; e0 < ne; e0 += nw * 8) {
    int eA = e0 + sub, eB = e0 + 4 + sub;
    int okA = eA < ne, okB = eB < ne;
    int sA = okA ? src[eA] : 0, dA = okA ? dst[eA] : 0;
    int sB = okB ? src[eB] : 0, dB = okB ? dst[eB] : 0;
    const float4* lpA = (const float4*)(xl + (long long)sA * D + q * 8);
    const float4* rpA = (const float4*)(xr + (long long)dA * D + q * 8);
    const float4* lpB = (const float4*)(xl + (long long)sB * D + q * 8);
    const float4* rpB = (const float4*)(xr + (long long)dB * D + q * 8);
    float4 lA0 = lpA[0], lA1 = lpA[1], rA0 = rpA[0], rA1 = rpA[1];
    float4 lB0 = lpB[0], lB1 = lpB[1], rB0 = rpB[0], rB1 = rpB[1];
    float z, vA = 0.f, vB = 0.f;
    z = lA0.x + rA0.x; vA += (z > 0.f ? z : 0.2f * z) * a0.x;
    z = lA0.y + rA0.y; vA += (z > 0.f ? z : 0.2f * z) * a0.y;
    z = lA0.z + rA0.z; vA += (z > 0.f ? z : 0.2f * z) * a0.z;
    z = lA0.w + rA0.w; vA += (z > 0.f ? z : 0.2f * z) * a0.w;
    z = lA1.x + rA1.x; vA += (z > 0.f ? z : 0.2f * z) * a1.x;
    z = lA1.y + rA1.y; vA += (z > 0.f ? z : 0.2f * z) * a1.y;
    z = lA1.z + rA1.z; vA += (z > 0.f ? z : 0.2f * z) * a1.z;
    z = lA1.w + rA1.w; vA += (z > 0.f ? z : 0.2f * z) * a1.w;
    z = lB0.x + rB0.x; vB += (z > 0.f ? z : 0.2f * z) * a0.x;
    z = lB0.y + rB0.y; vB += (z > 0.f ? z : 0.2f * z) * a0.y;
    z = lB0.z + rB0.z; vB += (z > 0.f ? z : 0.2f * z) * a0.z;
    z = lB0.w + rB0.w; vB += (z > 0.f ? z : 0.2f * z) * a0.w;
    z = lB1.x + rB1.x; vB += (z > 0.f ? z : 0.2f * z) * a1.x;
    z = lB1.y + rB1.y; vB += (z > 0.f ? z : 0.2f * z) * a1.y;
    z = lB1.z + rB1.z; vB += (z > 0.f ? z : 0.2f * z) * a1.z;
    z = lB1.w + rB1.w; vB += (z > 0.f ? z : 0.2f * z) * a1.w;
#pragma unroll
    for (int o = 8; o > 0; o >>= 1) vA += __shfl_xor(vA, o, 64);
#pragma unroll
    for (int o = 8; o > 0; o >>= 1) vB += __shfl_xor(vB, o, 64);
    if (q == 0) {
      if (okA) { e_sc[eA] = vA; atomicMax(&m_enc[dA], encf(vA)); }
      if (okB) { e_sc[eB] = vB; atomicMax(&m_enc[dB], encf(vB)); }
    }
  }
}

// ---------- edge pass 2: denominator ----------

__global__ __launch_bounds__(256) void seg_expsum(
    const float* __restrict__ e_sc, const int* __restrict__ dst,
    const unsigned int* __restrict__ m_enc, float* __restrict__ s_sum, int ne) {
  int i = blockIdx.x * 256 + threadIdx.x;
  if (i < ne) {
    int d_ = dst[i];
    float ex = expf(e_sc[i] - decf(m_enc[d_]));
    atomicAdd(&s_sum[d_], ex);
  }
}

// ---------- edge pass 3a: per-source scalar coefficients ----------

__global__ __launch_bounds__(256) void edge_coef(
    const float* __restrict__ e_sc, const int* __restrict__ src,
    const int* __restrict__ dst, const unsigned int* __restrict__ m_enc,
    const float* __restrict__ s_sum, float* __restrict__ coef, int ne) {
  int i = blockIdx.x * 256 + threadIdx.x;
  if (i < ne) {
    int d_ = dst[i];
    float w = expf(e_sc[i] - decf(m_enc[d_])) / s_sum[d_];
    atomicAdd(&coef[src[i]], w);
  }
}

// ---------- edge pass 3b: g_acc[d] = sum_s coef[s] * xl[s][d] ----------

__global__ __launch_bounds__(256) void weighted_sum(
    const float* __restrict__ xl, const float* __restrict__ coef,
    float* __restrict__ g_acc, int ns) {
  __shared__ float red[4][D];
  int lane = threadIdx.x & 63;
  int wv = threadIdx.x >> 6;
  int wid = blockIdx.x * 4 + wv;
  int nw = gridDim.x * 4;
  float ax = 0.f, ay = 0.f;
  for (int s = wid; s < ns; s += nw) {
    float w = coef[s];
    float2 x2 = ((const float2*)(xl + (long long)s * D))[lane];
    ax += w * x2.x;
    ay += w * x2.y;
  }
  red[wv][2 * lane] = ax;
  red[wv][2 * lane + 1] = ay;
  __syncthreads();
  if (threadIdx.x < D) {
    float t = red[0][threadIdx.x] + red[1][threadIdx.x] + red[2][threadIdx.x] +
              red[3][threadIdx.x];
    atomicAdd(&g_acc[threadIdx.x], t);
  }
}

// ---------- init: g -> vin0, keys, gates0 (h0=c0=0), h1,c1, hidden0 ----------

__global__ __launch_bounds__(256) void init_chain(
    const float* __restrict__ g_acc, const float* __restrict__ conv_bias,
    const float* __restrict__ Wih, const float* __restrict__ bih,
    const float* __restrict__ bhh, const float* __restrict__ W1,
    const float* __restrict__ b1, float* __restrict__ st_h,
    float* __restrict__ st_c, float* __restrict__ st_hidden,
    unsigned int* __restrict__ st_keys, float nm) {
  __shared__ float vin[D], hh[D], gts[4 * D];
  int tid = threadIdx.x;
  if (tid < D) vin[tid] = g_acc[tid] / nm + conv_bias[tid];
  if (tid < 8) {
    unsigned int x0 = 0u, x1 = (unsigned int)tid;
    tf2x32(0u, 42u, x0, x1);
    st_keys[2 * tid] = x0;
    st_keys[2 * tid + 1] = x1;
  }
  __syncthreads();
  for (int r = tid; r < 4 * D; r += 256) {
    const float4* wi = (const float4*)(Wih + (long long)r * D);
    float s0 = 0.f, s1 = 0.f, s2 = 0.f, s3 = 0.f;
#pragma unroll 8
    for (int k = 0; k < 32; ++k) {
      float4 w = wi[k];
      s0 += w.x * vin[4 * k];
      s1 += w.y * vin[4 * k + 1];
      s2 += w.z * vin[4 * k + 2];
      s3 += w.w * vin[4 * k + 3];
    }
    gts[r] = ((s0 + s1) + (s2 + s3)) + bih[r] + bhh[r];  // h0 = 0
  }
  __syncthreads();
  if (tid < D) {
    float i_ = 1.f / (1.f + expf(-gts[tid]));
    float g_ = tanhf(gts[2 * D + tid]);
    float o_ = 1.f / (1.f + expf(-gts[3 * D + tid]));
    float cn = i_ * g_;  // f*c0 = 0
    float hn = o_ * tanhf(cn);
    st_c[tid] = cn;
    st_h[tid] = hn;
    hh[tid] = hn;
  }
  __syncthreads();
  if (tid < D) {
    const float4* w = (const float4*)(W1 + tid * D);
    float s0 = 0.f, s1 = 0.f, s2 = 0.f, s3 = 0.f;
#pragma unroll 8
    for (int k = 0; k < 32; ++k) {
      float4 ww = w[k];
      s0 += ww.x * hh[4 * k];
      s1 += ww.y * hh[4 * k + 1];
      s2 += ww.z * hh[4 * k + 2];
      s3 += ww.w * hh[4 * k + 3];
    }
    st_hidden[tid] = fmaxf(((s0 + s1) + (s2 + s3)) + b1[tid], 0.f);
  }
}

// ---------- per-step fused: logits+gumbel (all blocks) + last-block tail ----------

__global__ __launch_bounds__(256) void chain_step(
    const float* __restrict__ Wih, const float* __restrict__ Whh,
    const float* __restrict__ bih, const float* __restrict__ bhh,
    const float* __restrict__ emb, const float* __restrict__ W1,
    const float* __restrict__ b1, const float* __restrict__ W2,
    const float* __restrict__ b2, float* __restrict__ st_h,
    float* __restrict__ st_c, float* __restrict__ st_hidden,
    const unsigned int* __restrict__ st_keys, float* __restrict__ sumexp,
    unsigned int* __restrict__ done, unsigned int* __restrict__ cand_enc,
    int* __restrict__ cand_j, float* __restrict__ cand_lg,
    float* __restrict__ out, int nm, int t) {
  __shared__ float hid[D];
  __shared__ unsigned int s_enc[256];
  __shared__ int s_j[256];
  __shared__ float s_lg[256];
  __shared__ float s_ex[256];
  __shared__ int s_flag;
  __shared__ float vin2[D], hc[D], gts[4 * D];
  int tid = threadIdx.x;
  if (tid < D) hid[tid] = st_hidden[tid];
  __syncthreads();
  unsigned int k0 = st_keys[2 * t], k1 = st_keys[2 * t + 1];
  unsigned int bestE = 0u;
  int bestJ = 0x7FFFFFFF;
  float bestL = 0.f, ex = 0.f;
  int j0 = blockIdx.x * 512 + tid;
#pragma unroll
  for (int half = 0; half < 2; ++half) {
    int j = j0 + half * 256;
    if (j < nm) {
      const float4* w = (const float4*)(W2 + (long long)j * D);
      float s0 = 0.f, s1 = 0.f, s2 = 0.f, s3 = 0.f;
#pragma unroll 8
      for (int k = 0; k < 32; ++k) {
        float4 ww = w[k];
        s0 += ww.x * hid[4 * k];
        s1 += ww.y * hid[4 * k + 1];
        s2 += ww.z * hid[4 * k + 2];
        s3 += ww.w * hid[4 * k + 3];
      }
      float lv = ((s0 + s1) + (s2 + s3)) + b2[j];
      ex += expf(lv);
      unsigned int x0 = 0u, x1 = (unsigned int)j;
      tf2x32(k0, k1, x0, x1);
      unsigned int bits = x0 ^ x1;
      float f = __uint_as_float((bits >> 9) | 0x3f800000u) - 1.0f;
      const float tiny = 1.1754943508222875e-38f;
      float u = fmaxf(tiny, f * (1.0f - tiny) + tiny);
      float pert = lv + (-logf(-logf(u)));
      unsigned int en = encf(pert);
      if (en > bestE || (en == bestE && j < bestJ)) {
        bestE = en; bestJ = j; bestL = lv;
      }
    }
  }
  s_enc[tid] = bestE; s_j[tid] = bestJ; s_lg[tid] = bestL; s_ex[tid] = ex;
  __syncthreads();
  for (int s = 128; s > 0; s >>= 1) {
    if (tid < s) {
      s_ex[tid] += s_ex[tid + s];
      unsigned int eo = s_enc[tid + s];
      if (eo > s_enc[tid] || (eo == s_enc[tid] && s_j[tid + s] < s_j[tid])) {
        s_enc[tid] = eo; s_j[tid] = s_j[tid + s]; s_lg[tid] = s_lg[tid + s];
      }
    }
    __syncthreads();
  }
  if (tid == 0) {
    cand_enc[blockIdx.x] = s_enc[0];
    cand_j[blockIdx.x] = s_j[0];
    cand_lg[blockIdx.x] = s_lg[0];
    atomicAdd(&sumexp[t], s_ex[0]);
    __threadfence();  // release: cand writes + atomics before done++
    unsigned int old = atomicAdd(&done[t], 1u);
    s_flag = (old == gridDim.x - 1);
  }
  __syncthreads();
  if (!s_flag) return;
  __threadfence();  // acquire: see other blocks' cand writes
  // ---- tail: last-finishing block ----
  int nb = (int)gridDim.x;
  unsigned int e2 = (tid < nb) ? cand_enc[tid] : 0u;
  int j2 = (tid < nb) ? cand_j[tid] : 0x7FFFFFFF;
  float l2 = (tid < nb) ? cand_lg[tid] : 0.f;
  s_enc[tid] = e2; s_j[tid] = j2; s_lg[tid] = l2;
  __syncthreads();
  for (int s = 128; s > 0; s >>= 1) {
    if (tid < s) {
      unsigned int eo = s_enc[tid + s];
      if (eo > s_enc[tid] || (eo == s_enc[tid] && s_j[tid + s] < s_j[tid])) {
        s_enc[tid] = eo; s_j[tid] = s_j[tid + s]; s_lg[tid] = s_lg[tid + s];
      }
    }
    __syncthreads();
  }
  int a = s_j[0];
  float lga = s_lg[0];
  if (a < 0 || a >= nm) a = 0;
  if (tid == 0) {
    float se = atomicAdd(&sumexp[t], 0.0f);  // coherent read
    out[t] = (float)a;
    out[8 + t] = lga - logf(se);
  }
  if (t < 7) {
    if (tid < D) {
      vin2[tid] = emb[(long long)a * D + tid];
      hc[tid] = st_h[tid];
    }
    __syncthreads();
    for (int r = tid; r < 4 * D; r += 256) {
      const float4* wi = (const float4*)(Wih + (long long)r * D);
      const float4* wh = (const float4*)(Whh + (long long)r * D);
      float s0 = 0.f, s1 = 0.f, s2 = 0.f, s3 = 0.f;
#pragma unroll 8
      for (int k = 0; k < 32; ++k) {
        float4 wa = wi[k], wb = wh[k];
        s0 += wa.x * vin2[4 * k] + wb.x * hc[4 * k];
        s1 += wa.y * vin2[4 * k + 1] + wb.y * hc[4 * k + 1];
        s2 += wa.z * vin2[4 * k + 2] + wb.z * hc[4 * k + 2];
        s3 += wa.w * vin2[4 * k + 3] + wb.w * hc[4 * k + 3];
      }
      gts[r] = ((s0 + s1) + (s2 + s3)) + bih[r] + bhh[r];
    }
    __syncthreads();
    if (tid < D) {
      float i_ = 1.f / (1.f + expf(-gts[tid]));
      float f_ = 1.f / (1.f + expf(-gts[D + tid]));
      float g_ = tanhf(gts[2 * D + tid]);
      float o_ = 1.f / (1.f + expf(-gts[3 * D + tid]));
      float cn = f_ * st_c[tid] + i_ * g_;
      float hn = o_ * tanhf(cn);
      st_c[tid] = cn;
      st_h[tid] = hn;
      hc[tid] = hn;
    }
    __syncthreads();
    if (tid < D) {
      const float4* w = (const float4*)(W1 + tid * D);
      float s0 = 0.f, s1 = 0.f, s2 = 0.f, s3 = 0.f;
#pragma unroll 8
      for (int k = 0; k < 32; ++k) {
        float4 ww = w[k];
        s0 += ww.x * hc[4 * k];
        s1 += ww.y * hc[4 * k + 1];
        s2 += ww.z * hc[4 * k + 2];
        s3 += ww.w * hc[4 * k + 3];
      }
      st_hidden[tid] = fmaxf(((s0 + s1) + (s2 + s3)) + b1[tid], 0.f);
    }
  } else {
    if (tid < D) {
      out[16 + tid] = st_h[tid];
      out[144 + tid] = st_c[tid];
    }
  }
}

// ---------- launch ----------

extern "C" void kernel_launch(void* const* d_in, const int* in_sizes, int n_in,
                              void* d_out, int out_size, void* d_ws, size_t ws_size,
                              hipStream_t stream) {
  const float* state_features = (const float*)d_in[0];
  const float* model_features = (const float*)d_in[1];
  const int* edge_index = (const int*)d_in[2];
  const float* W_l = (const float*)d_in[3];
  const float* W_r = (const float*)d_in[4];
  const float* att = (const float*)d_in[5];
  const float* conv_bias = (const float*)d_in[6];
  const float* Wih = (const float*)d_in[7];
  const float* Whh = (const float*)d_in[8];
  const float* bih = (const float*)d_in[9];
  const float* bhh = (const float*)d_in[10];
  const float* W1 = (const float*)d_in[11];
  const float* b1 = (const float*)d_in[12];
  const float* W2 = (const float*)d_in[13];
  const float* b2 = (const float*)d_in[14];
  const float* emb = (const float*)d_in[15];
  float* out = (float*)d_out;

  const int NS = in_sizes[0] / D;
  const int NM = in_sizes[1] / D;
  const int E = in_sizes[2] / 2;

  char* ws = (char*)d_ws;
  size_t off = 0;
  auto alloc = [&](size_t bytes) -> void* {
    void* p = ws + off;
    off = (off + bytes + 255) & ~(size_t)255;
    return p;
  };
  float* xl = (float*)alloc((size_t)NS * D * 4);
  float* xr = (float*)alloc((size_t)NM * D * 4);
  float* e_sc = (float*)alloc((size_t)E * 4);
  int* src32 = (int*)alloc((size_t)E * 4);
  int* dst32 = (int*)alloc((size_t)E * 4);
  size_t zstart = off;
  unsigned int* m_enc = (unsigned int*)alloc((size_t)NM * 4);
  float* s_sum = (float*)alloc((size_t)NM * 4);
  float* coef = (float*)alloc((size_t)NS * 4);
  float* g_acc = (float*)alloc(D * 4);
  float* st_h = (float*)alloc(D * 4);
  float* st_c = (float*)alloc(D * 4);
  float* st_hidden = (float*)alloc(D * 4);
  unsigned int* st_keys = (unsigned int*)alloc(16 * 4);
  float* st_sumexp = (float*)alloc(8 * 4);
  unsigned int* st_done = (unsigned int*)alloc(8 * 4);
  unsigned int* cand_enc = (unsigned int*)alloc(128 * 4);
  int* cand_j = (int*)alloc(128 * 4);
  float* cand_lg = (float*)alloc(128 * 4);
  size_t zend = off;

  hipMemsetAsync(ws + zstart, 0, zend - zstart, stream);

  norm_edges<<<512, 256, 0, stream>>>(edge_index, src32, dst32, E, NS, NM);

  gemm128<<<(NS + 127) / 128, 256, 0, stream>>>(state_features, W_l, xl, NS);
  gemm128<<<(NM + 127) / 128, 256, 0, stream>>>(model_features, W_r, xr, NM);

  edge_scores<<<2048, 256, 0, stream>>>(xl, xr, src32, dst32, att, e_sc, m_enc, E);
  seg_expsum<<<(E + 255) / 256, 256, 0, stream>>>(e_sc, dst32, m_enc, s_sum, E);
  edge_coef<<<(E + 255) / 256, 256, 0, stream>>>(e_sc, src32, dst32, m_enc,
                                                 s_sum, coef, E);
  weighted_sum<<<1024, 256, 0, stream>>>(xl, coef, g_acc, NS);

  init_chain<<<1, 256, 0, stream>>>(g_acc, conv_bias, Wih, bih, bhh, W1, b1,
                                    st_h, st_c, st_hidden, st_keys, (float)NM);

  const int NB = (NM + 511) / 512;  // 98
  for (int t = 0; t < 8; ++t) {
    chain_step<<<NB, 256, 0, stream>>>(Wih, Whh, bih, bhh, emb, W1, b1, W2, b2,
                                       st_h, st_c, st_hidden, st_keys,
                                       st_sumexp, st_done, cand_enc, cand_j,
                                       cand_lg, out, NM, t);
  }
}

// Round 6
// 613.409 us; speedup vs baseline: 1.1997x; 1.1997x over previous
//
#include <hip/hip_runtime.h>

#define D 128
#define WTS 132  // padded LDS row stride for gemm staging

// ---------- helpers ----------

__device__ __forceinline__ unsigned int encf(float f) {
  unsigned int u = __float_as_uint(f);
  return (u & 0x80000000u) ? ~u : (u | 0x80000000u);
}
__device__ __forceinline__ float decf(unsigned int e) {
  return __uint_as_float((e & 0x80000000u) ? (e & 0x7FFFFFFFu) : ~e);
}
__device__ __forceinline__ unsigned short f2bf(float f) {
  unsigned int u = __float_as_uint(f);
  u += 0x7FFFu + ((u >> 16) & 1u);  // rne
  return (unsigned short)(u >> 16);
}
__device__ __forceinline__ float bf_lo(unsigned int u) {
  return __uint_as_float(u << 16);
}
__device__ __forceinline__ float bf_hi(unsigned int u) {
  return __uint_as_float(u & 0xFFFF0000u);
}

// JAX threefry2x32 (20 rounds), exact.
__device__ __forceinline__ void tf2x32(unsigned int k0, unsigned int k1,
                                       unsigned int& x0, unsigned int& x1) {
  unsigned int ks[3] = {k0, k1, k0 ^ k1 ^ 0x1BD11BDAu};
  x0 += ks[0]; x1 += ks[1];
  const unsigned int rotA[4] = {13u, 15u, 26u, 6u};
  const unsigned int rotB[4] = {17u, 29u, 16u, 24u};
#pragma unroll
  for (int g = 0; g < 5; ++g) {
    const unsigned int* rot = (g & 1) ? rotB : rotA;
#pragma unroll
    for (int i = 0; i < 4; ++i) {
      x0 += x1;
      x1 = (x1 << rot[i]) | (x1 >> (32u - rot[i]));
      x1 ^= x0;
    }
    x0 += ks[(g + 1) % 3];
    x1 += ks[(g + 2) % 3] + (unsigned int)(g + 1);
  }
}

// ---------- edge index normalization (int32 vs int64 runtime detect) ----------

__global__ __launch_bounds__(256) void norm_edges(const int* __restrict__ ei,
                                                  int* __restrict__ src32,
                                                  int* __restrict__ dst32,
                                                  int ne, int ns, int nm) {
  __shared__ int is64;
  if (threadIdx.x == 0) {
    int any = 0;
    for (int i = 1; i < 256; i += 2) any |= ei[i];
    is64 = (any == 0);
  }
  __syncthreads();
  int flag = is64;
  for (int i = blockIdx.x * 256 + threadIdx.x; i < ne; i += gridDim.x * 256) {
    int s = flag ? ei[2 * i] : ei[i];
    int d = flag ? ei[2 * ne + 2 * i] : ei[ne + i];
    s = s < 0 ? 0 : (s >= ns ? ns - 1 : s);
    d = d < 0 ? 0 : (d >= nm ? nm - 1 : d);
    src32[i] = s;
    dst32[i] = d;
  }
}

// ---------- GEMM v2: Y = X @ W^T; optional fp32 + bf16 outputs ----------

__global__ __launch_bounds__(256) void gemm128(const float* __restrict__ X,
                                               const float* __restrict__ W,
                                               float* __restrict__ Yf,
                                               unsigned short* __restrict__ Yh,
                                               int N) {
  __shared__ float WT[64 * WTS];  // WT[k'][c]
  int tid = threadIdx.x;
  int q = tid & 15;
  int rg = tid >> 4;

  for (long long r0 = (long long)blockIdx.x * 128; r0 < N;
       r0 += (long long)gridDim.x * 128) {
    float acc[8][8];
#pragma unroll
    for (int r = 0; r < 8; ++r)
#pragma unroll
      for (int c = 0; c < 8; ++c) acc[r][c] = 0.f;

    long long rbase = r0 + (long long)rg * 8;

#pragma unroll
    for (int phase = 0; phase < 2; ++phase) {
      const int kbase = phase * 64;
      __syncthreads();
      for (int i = tid; i < 2048; i += 256) {
        int c = i >> 4;
        int j = i & 15;
        float4 w4 = *(const float4*)(W + c * D + kbase + 4 * j);
        WT[(4 * j + 0) * WTS + c] = w4.x;
        WT[(4 * j + 1) * WTS + c] = w4.y;
        WT[(4 * j + 2) * WTS + c] = w4.z;
        WT[(4 * j + 3) * WTS + c] = w4.w;
      }
      __syncthreads();

      for (int k4 = 0; k4 < 64; k4 += 4) {
        float4 xr_[8];
#pragma unroll
        for (int r = 0; r < 8; ++r) {
          long long rr = rbase + r;
          if (rr >= N) rr = N - 1;
          xr_[r] = *(const float4*)(X + rr * D + kbase + k4);
        }
#pragma unroll
        for (int kk = 0; kk < 4; ++kk) {
          float4 wa = *(const float4*)(WT + (k4 + kk) * WTS + 4 * q);
          float4 wb = *(const float4*)(WT + (k4 + kk) * WTS + 64 + 4 * q);
#pragma unroll
          for (int r = 0; r < 8; ++r) {
            float xv = (&xr_[r].x)[kk];
            acc[r][0] += xv * wa.x; acc[r][1] += xv * wa.y;
            acc[r][2] += xv * wa.z; acc[r][3] += xv * wa.w;
            acc[r][4] += xv * wb.x; acc[r][5] += xv * wb.y;
            acc[r][6] += xv * wb.z; acc[r][7] += xv * wb.w;
          }
        }
      }
    }

#pragma unroll
    for (int r = 0; r < 8; ++r) {
      long long rr = rbase + r;
      if (rr < N) {
        if (Yf) {
          float* yp = Yf + rr * D;
          *(float4*)(yp + 4 * q) =
              make_float4(acc[r][0], acc[r][1], acc[r][2], acc[r][3]);
          *(float4*)(yp + 64 + 4 * q) =
              make_float4(acc[r][4], acc[r][5], acc[r][6], acc[r][7]);
        }
        if (Yh) {
          unsigned short* hp = Yh + rr * D;
          uint2 pa, pb;
          pa.x = (unsigned int)f2bf(acc[r][0]) | ((unsigned int)f2bf(acc[r][1]) << 16);
          pa.y = (unsigned int)f2bf(acc[r][2]) | ((unsigned int)f2bf(acc[r][3]) << 16);
          pb.x = (unsigned int)f2bf(acc[r][4]) | ((unsigned int)f2bf(acc[r][5]) << 16);
          pb.y = (unsigned int)f2bf(acc[r][6]) | ((unsigned int)f2bf(acc[r][7]) << 16);
          *(uint2*)(hp + 4 * q) = pa;
          *(uint2*)(hp + 64 + 4 * q) = pb;
        }
      }
    }
  }
}

// ---------- edge pass 1: scores + segment max (bf16 rows, quarter-wave/edge x2) --

__global__ __launch_bounds__(256) void edge_scores(
    const unsigned short* __restrict__ xlh, const unsigned short* __restrict__ xrh,
    const int* __restrict__ src, const int* __restrict__ dst,
    const float* __restrict__ att, float* __restrict__ e_sc,
    unsigned int* __restrict__ m_enc, int ne) {
  int tid = threadIdx.x;
  int lane = tid & 63;
  int q = lane & 15;
  int sub = lane >> 4;
  int wid = (blockIdx.x * 256 + tid) >> 6;
  int nw = (gridDim.x * 256) >> 6;
  float4 a0 = ((const float4*)att)[2 * q];
  float4 a1 = ((const float4*)att)[2 * q + 1];
  for (int e0 = wid * 8; e0 < ne; e0 += nw * 8) {
    int eA = e0 + sub, eB = e0 + 4 + sub;
    int okA = eA < ne, okB = eB < ne;
    int sA = okA ? src[eA] : 0, dA = okA ? dst[eA] : 0;
    int sB = okB ? src[eB] : 0, dB = okB ? dst[eB] : 0;
    uint4 lA = *(const uint4*)(xlh + (long long)sA * D + q * 8);
    uint4 rA = *(const uint4*)(xrh + (long long)dA * D + q * 8);
    uint4 lB = *(const uint4*)(xlh + (long long)sB * D + q * 8);
    uint4 rB = *(const uint4*)(xrh + (long long)dB * D + q * 8);
    float z, vA = 0.f, vB = 0.f;
    z = bf_lo(lA.x) + bf_lo(rA.x); vA += (z > 0.f ? z : 0.2f * z) * a0.x;
    z = bf_hi(lA.x) + bf_hi(rA.x); vA += (z > 0.f ? z : 0.2f * z) * a0.y;
    z = bf_lo(lA.y) + bf_lo(rA.y); vA += (z > 0.f ? z : 0.2f * z) * a0.z;
    z = bf_hi(lA.y) + bf_hi(rA.y); vA += (z > 0.f ? z : 0.2f * z) * a0.w;
    z = bf_lo(lA.z) + bf_lo(rA.z); vA += (z > 0.f ? z : 0.2f * z) * a1.x;
    z = bf_hi(lA.z) + bf_hi(rA.z); vA += (z > 0.f ? z : 0.2f * z) * a1.y;
    z = bf_lo(lA.w) + bf_lo(rA.w); vA += (z > 0.f ? z : 0.2f * z) * a1.z;
    z = bf_hi(lA.w) + bf_hi(rA.w); vA += (z > 0.f ? z : 0.2f * z) * a1.w;
    z = bf_lo(lB.x) + bf_lo(rB.x); vB += (z > 0.f ? z : 0.2f * z) * a0.x;
    z = bf_hi(lB.x) + bf_hi(rB.x); vB += (z > 0.f ? z : 0.2f * z) * a0.y;
    z = bf_lo(lB.y) + bf_lo(rB.y); vB += (z > 0.f ? z : 0.2f * z) * a0.z;
    z = bf_hi(lB.y) + bf_hi(rB.y); vB += (z > 0.f ? z : 0.2f * z) * a0.w;
    z = bf_lo(lB.z) + bf_lo(rB.z); vB += (z > 0.f ? z : 0.2f * z) * a1.x;
    z = bf_hi(lB.z) + bf_hi(rB.z); vB += (z > 0.f ? z : 0.2f * z) * a1.y;
    z = bf_lo(lB.w) + bf_lo(rB.w); vB += (z > 0.f ? z : 0.2f * z) * a1.z;
    z = bf_hi(lB.w) + bf_hi(rB.w); vB += (z > 0.f ? z : 0.2f * z) * a1.w;
#pragma unroll
    for (int o = 8; o > 0; o >>= 1) vA += __shfl_xor(vA, o, 64);
#pragma unroll
    for (int o = 8; o > 0; o >>= 1) vB += __shfl_xor(vB, o, 64);
    if (q == 0) {
      if (okA) { e_sc[eA] = vA; atomicMax(&m_enc[dA], encf(vA)); }
      if (okB) { e_sc[eB] = vB; atomicMax(&m_enc[dB], encf(vB)); }
    }
  }
}

// ---------- edge pass 2: denominator ----------

__global__ __launch_bounds__(256) void seg_expsum(
    const float* __restrict__ e_sc, const int* __restrict__ dst,
    const unsigned int* __restrict__ m_enc, float* __restrict__ s_sum, int ne) {
  int i = blockIdx.x * 256 + threadIdx.x;
  if (i < ne) {
    int d_ = dst[i];
    float ex = expf(e_sc[i] - decf(m_enc[d_]));
    atomicAdd(&s_sum[d_], ex);
  }
}

// ---------- edge pass 3a: per-source scalar coefficients ----------

__global__ __launch_bounds__(256) void edge_coef(
    const float* __restrict__ e_sc, const int* __restrict__ src,
    const int* __restrict__ dst, const unsigned int* __restrict__ m_enc,
    const float* __restrict__ s_sum, float* __restrict__ coef, int ne) {
  int i = blockIdx.x * 256 + threadIdx.x;
  if (i < ne) {
    int d_ = dst[i];
    float w = expf(e_sc[i] - decf(m_enc[d_])) / s_sum[d_];
    atomicAdd(&coef[src[i]], w);
  }
}

// ---------- edge pass 3b: g_acc[d] = sum_s coef[s] * xl[s][d] ----------

__global__ __launch_bounds__(256) void weighted_sum(
    const float* __restrict__ xl, const float* __restrict__ coef,
    float* __restrict__ g_acc, int ns) {
  __shared__ float red[4][D];
  int lane = threadIdx.x & 63;
  int wv = threadIdx.x >> 6;
  int wid = blockIdx.x * 4 + wv;
  int nw = gridDim.x * 4;
  float ax = 0.f, ay = 0.f;
  for (int s = wid; s < ns; s += nw) {
    float w = coef[s];
    float2 x2 = ((const float2*)(xl + (long long)s * D))[lane];
    ax += w * x2.x;
    ay += w * x2.y;
  }
  red[wv][2 * lane] = ax;
  red[wv][2 * lane + 1] = ay;
  __syncthreads();
  if (threadIdx.x < D) {
    float t = red[0][threadIdx.x] + red[1][threadIdx.x] + red[2][threadIdx.x] +
              red[3][threadIdx.x];
    atomicAdd(&g_acc[threadIdx.x], t);
  }
}

// ---------- init: g, keys, h=c=0 ----------

__global__ __launch_bounds__(128) void init_state(
    const float* __restrict__ g_acc, const float* __restrict__ conv_bias,
    float* __restrict__ inp, float* __restrict__ h, float* __restrict__ c,
    unsigned int* __restrict__ keys, float nm) {
  int d = threadIdx.x;
  inp[d] = g_acc[d] / nm + conv_bias[d];
  h[d] = 0.f;
  c[d] = 0.f;
  if (d == 0) {
#pragma unroll
    for (int t = 0; t < 8; ++t) {
      unsigned int x0 = 0u, x1 = (unsigned int)t;
      tf2x32(0u, 42u, x0, x1);
      keys[2 * t] = x0;
      keys[2 * t + 1] = x1;
    }
  }
}

// ---------- per-step: gates (+ finalize previous step's outputs) ----------

__global__ __launch_bounds__(256) void lstm_gates(
    const float* __restrict__ Wih, const float* __restrict__ Whh,
    const float* __restrict__ bih, const float* __restrict__ bhh,
    const float* __restrict__ emb, const float* __restrict__ g_inp,
    const float* __restrict__ h, float* __restrict__ gates,
    const unsigned long long* __restrict__ amax,
    const float* __restrict__ sumexp, const float* __restrict__ logits,
    float* __restrict__ out, int t, int nm) {
  __shared__ float vin[D], vh[D];
  __shared__ float part[64][4];
  int tid = threadIdx.x;
  int a = 0;
  if (t > 0) {
    unsigned long long p = amax[t - 1];
    a = (int)(0xFFFFFFFFu - (unsigned int)(p & 0xFFFFFFFFull));
    a = a < 0 ? 0 : (a >= nm ? nm - 1 : a);
  }
  if (tid < D)
    vin[tid] = (t == 0) ? g_inp[tid] : emb[(long long)a * D + tid];
  else
    vh[tid - D] = h[tid - D];
  if (t > 0 && blockIdx.x == 0 && tid == 255) {
    out[t - 1] = (float)a;
    out[8 + t - 1] = logits[a] - logf(sumexp[t - 1]);
  }
  __syncthreads();
  int r = blockIdx.x * 64 + (tid >> 2);
  int q = tid & 3;
  const float4* wi = (const float4*)(Wih + (long long)r * D + q * 32);
  const float4* wh = (const float4*)(Whh + (long long)r * D + q * 32);
  float s = 0.f;
#pragma unroll
  for (int k = 0; k < 8; ++k) {
    float4 a4 = wi[k], b4 = wh[k];
    int kb = q * 32 + 4 * k;
    s += a4.x * vin[kb] + a4.y * vin[kb + 1] + a4.z * vin[kb + 2] + a4.w * vin[kb + 3];
    s += b4.x * vh[kb] + b4.y * vh[kb + 1] + b4.z * vh[kb + 2] + b4.w * vh[kb + 3];
  }
  part[tid >> 2][q] = s;
  __syncthreads();
  if (q == 0) {
    int rr = tid >> 2;
    gates[r] = part[rr][0] + part[rr][1] + part[rr][2] + part[rr][3] + bih[r] + bhh[r];
  }
}

// ---------- per-step: cell + hidden (redundant per block) + logits/gumbel ----------

__global__ __launch_bounds__(256) void logits_fused(
    const float* __restrict__ gates, const float* __restrict__ c_in,
    float* __restrict__ c_out, float* __restrict__ h_out,
    const float* __restrict__ W1, const float* __restrict__ b1,
    const float* __restrict__ W2, const float* __restrict__ b2,
    float* __restrict__ logits, unsigned long long* __restrict__ amax,
    float* __restrict__ sumexp, const unsigned int* __restrict__ keys,
    int nm, int t) {
  __shared__ float hn_s[D];
  __shared__ float hid_s[D];
  __shared__ float rs[256];
  int tid = threadIdx.x;
  if (tid < D) {
    float gi = gates[tid], gf = gates[D + tid], gg = gates[2 * D + tid],
          go = gates[3 * D + tid];
    float i_ = 1.f / (1.f + expf(-gi));
    float f_ = 1.f / (1.f + expf(-gf));
    float g_ = tanhf(gg);
    float o_ = 1.f / (1.f + expf(-go));
    float cn = f_ * c_in[tid] + i_ * g_;
    float hn = o_ * tanhf(cn);
    hn_s[tid] = hn;
    if (blockIdx.x == 0) {
      c_out[tid] = cn;
      h_out[tid] = hn;
    }
  }
  __syncthreads();
  if (tid < D) {
    const float4* w = (const float4*)(W1 + tid * D);
    float s0 = 0.f, s1 = 0.f, s2 = 0.f, s3 = 0.f;
#pragma unroll 8
    for (int k = 0; k < 32; ++k) {
      float4 ww = w[k];
      s0 += ww.x * hn_s[4 * k];
      s1 += ww.y * hn_s[4 * k + 1];
      s2 += ww.z * hn_s[4 * k + 2];
      s3 += ww.w * hn_s[4 * k + 3];
    }
    float s = ((s0 + s1) + (s2 + s3)) + b1[tid];
    hid_s[tid] = fmaxf(s, 0.f);
  }
  __syncthreads();
  int j = blockIdx.x * 256 + tid;
  float ex = 0.f;
  if (j < nm) {
    const float4* w = (const float4*)(W2 + (long long)j * D);
    float s0 = 0.f, s1 = 0.f, s2 = 0.f, s3 = 0.f;
#pragma unroll 8
    for (int k = 0; k < 32; ++k) {
      float4 ww = w[k];
      s0 += ww.x * hid_s[4 * k];
      s1 += ww.y * hid_s[4 * k + 1];
      s2 += ww.z * hid_s[4 * k + 2];
      s3 += ww.w * hid_s[4 * k + 3];
    }
    float lv = ((s0 + s1) + (s2 + s3)) + b2[j];
    logits[j] = lv;
    ex = expf(lv);
    unsigned int x0 = 0u, x1 = (unsigned int)j;
    tf2x32(keys[2 * t], keys[2 * t + 1], x0, x1);
    unsigned int bits = x0 ^ x1;
    float f = __uint_as_float((bits >> 9) | 0x3f800000u) - 1.0f;
    const float tiny = 1.1754943508222875e-38f;
    float u = fmaxf(tiny, f * (1.0f - tiny) + tiny);
    float gmb = -logf(-logf(u));
    float pert = lv + gmb;
    unsigned long long pk = ((unsigned long long)encf(pert) << 32) |
                            (unsigned long long)(0xFFFFFFFFu - (unsigned int)j);
    atomicMax(&amax[t], pk);
  }
  rs[tid] = ex;
  __syncthreads();
  for (int s = 128; s > 0; s >>= 1) {
    if (tid < s) rs[tid] += rs[tid + s];
    __syncthreads();
  }
  if (tid == 0) atomicAdd(&sumexp[t], rs[0]);
}

// ---------- final outputs ----------

__global__ __launch_bounds__(128) void final_out(
    const float* __restrict__ h, const float* __restrict__ c,
    const float* __restrict__ logits, const unsigned long long* __restrict__ amax,
    const float* __restrict__ sumexp, float* __restrict__ out, int nm) {
  int tid = threadIdx.x;
  if (tid == 0) {
    unsigned long long p = amax[7];
    int a = (int)(0xFFFFFFFFu - (unsigned int)(p & 0xFFFFFFFFull));
    a = a < 0 ? 0 : (a >= nm ? nm - 1 : a);
    out[7] = (float)a;
    out[15] = logits[a] - logf(sumexp[7]);
  }
  out[16 + tid] = h[tid];
  out[144 + tid] = c[tid];
}

// ---------- launch ----------

extern "C" void kernel_launch(void* const* d_in, const int* in_sizes, int n_in,
                              void* d_out, int out_size, void* d_ws, size_t ws_size,
                              hipStream_t stream) {
  const float* state_features = (const float*)d_in[0];
  const float* model_features = (const float*)d_in[1];
  const int* edge_index = (const int*)d_in[2];
  const float* W_l = (const float*)d_in[3];
  const float* W_r = (const float*)d_in[4];
  const float* att = (const float*)d_in[5];
  const float* conv_bias = (const float*)d_in[6];
  const float* Wih = (const float*)d_in[7];
  const float* Whh = (const float*)d_in[8];
  const float* bih = (const float*)d_in[9];
  const float* bhh = (const float*)d_in[10];
  const float* W1 = (const float*)d_in[11];
  const float* b1 = (const float*)d_in[12];
  const float* W2 = (const float*)d_in[13];
  const float* b2 = (const float*)d_in[14];
  const float* emb = (const float*)d_in[15];
  float* out = (float*)d_out;

  const int NS = in_sizes[0] / D;
  const int NM = in_sizes[1] / D;
  const int E = in_sizes[2] / 2;

  char* ws = (char*)d_ws;
  size_t off = 0;
  auto alloc = [&](size_t bytes) -> void* {
    void* p = ws + off;
    off = (off + bytes + 255) & ~(size_t)255;
    return p;
  };
  float* xl = (float*)alloc((size_t)NS * D * 4);
  unsigned short* xlh = (unsigned short*)alloc((size_t)NS * D * 2);
  unsigned short* xrh = (unsigned short*)alloc((size_t)NM * D * 2);
  float* e_sc = (float*)alloc((size_t)E * 4);
  int* src32 = (int*)alloc((size_t)E * 4);
  int* dst32 = (int*)alloc((size_t)E * 4);
  size_t zstart = off;
  unsigned int* m_enc = (unsigned int*)alloc((size_t)NM * 4);
  float* s_sum = (float*)alloc((size_t)NM * 4);
  float* coef = (float*)alloc((size_t)NS * 4);
  float* logits = (float*)alloc((size_t)NM * 4);
  float* g_acc = (float*)alloc(D * 4);
  float* st_inp = (float*)alloc(D * 4);
  float* st_h = (float*)alloc(D * 4);
  float* st_c = (float*)alloc(2 * D * 4);
  float* st_gates = (float*)alloc(4 * D * 4);
  unsigned int* st_keys = (unsigned int*)alloc(16 * 4);
  float* st_sumexp = (float*)alloc(8 * 4);
  unsigned long long* st_amax = (unsigned long long*)alloc(8 * 8);
  size_t zend = off;

  hipMemsetAsync(ws + zstart, 0, zend - zstart, stream);

  norm_edges<<<512, 256, 0, stream>>>(edge_index, src32, dst32, E, NS, NM);

  gemm128<<<(NS + 127) / 128, 256, 0, stream>>>(state_features, W_l, xl, xlh, NS);
  gemm128<<<(NM + 127) / 128, 256, 0, stream>>>(model_features, W_r,
                                                (float*)nullptr, xrh, NM);

  edge_scores<<<2048, 256, 0, stream>>>(xlh, xrh, src32, dst32, att, e_sc,
                                        m_enc, E);
  seg_expsum<<<(E + 255) / 256, 256, 0, stream>>>(e_sc, dst32, m_enc, s_sum, E);
  edge_coef<<<(E + 255) / 256, 256, 0, stream>>>(e_sc, src32, dst32, m_enc,
                                                 s_sum, coef, E);
  weighted_sum<<<1024, 256, 0, stream>>>(xl, coef, g_acc, NS);

  init_state<<<1, 128, 0, stream>>>(g_acc, conv_bias, st_inp, st_h, st_c,
                                    st_keys, (float)NM);

  for (int t = 0; t < 8; ++t) {
    const float* c_in = st_c + (t & 1) * D;
    float* c_out = st_c + ((t + 1) & 1) * D;
    lstm_gates<<<8, 256, 0, stream>>>(Wih, Whh, bih, bhh, emb, st_inp, st_h,
                                      st_gates, st_amax, st_sumexp, logits, out,
                                      t, NM);
    logits_fused<<<(NM + 255) / 256, 256, 0, stream>>>(
        st_gates, c_in, c_out, st_h, W1, b1, W2, b2, logits, st_amax,
        st_sumexp, st_keys, NM, t);
  }

  final_out<<<1, 128, 0, stream>>>(st_h, st_c, logits, st_amax, st_sumexp, out,
                                   NM);
}